// Round 1
// baseline (337.255 us; speedup 1.0000x reference)
//
#include <hip/hip_runtime.h>

// GCN 2-layer forward. CSR-gather, bf16 payloads (stride-64, 128 B rows),
// 4-edges-per-gather aggregation. hs1 = x@W1 (unscaled; mm1 fused with part,
// build pre-scales hs1 by dinv). Pipeline (5 dispatches): memset -> partmm1 ->
// build(+scale) -> agg1 -> mm2 -> agg2.
//
// R1: re-granularized the latency-bound phases. CHUNK_P 4096->2048 (782
// partition blocks, 8 edges/thread) and buckets 256->128 nodes (BSH 7,
// 782 build blocks). Theory: partmm1's 65us was a thin partition tail
// (391 blocks = 19% occupancy) after the GEMM blocks finished at ~20us;
// build has the same structure. 2x blocks + half per-block serial chain.

#define FIN 128
#define F1  64
#define F2  41
#define FP  64     // payload row stride (bf16 elems): 128 B, 2 lines, aligned

#define BSH    7                 // bucket = dst >> 7 (128 nodes/bucket)
#define BCAP   3072              // per-bucket edge window (mean 2048, >20 sigma)
#define NBMAX  1024              // max buckets (n <= 131072)
#define CHUNK_P 2048             // edges per part block (8/thread)

#define MT 128                   // GEMM M-tile
#define KC 16                    // GEMM K-chunk

#define SMEM_BYTES 24576         // union: part 21.5 KB / mm1 24.6 KB -> 6 blk/CU

__device__ __forceinline__ unsigned short f2bf(float f) {
    unsigned u = __builtin_bit_cast(unsigned, f);
    u += 0x7FFFu + ((u >> 16) & 1u);           // RNE
    return (unsigned short)(u >> 16);
}
__device__ __forceinline__ float bf2f(unsigned short h) {
    unsigned u = ((unsigned)h) << 16;
    return __builtin_bit_cast(float, u);
}

// ---- fused: blocks [0,nchunks) = edge partition; rest = layer-1 GEMM -------
__global__ __launch_bounds__(256) void k_partmm1(
    const int* __restrict__ src, const int* __restrict__ dst,
    int* __restrict__ gcur, int* __restrict__ pairs, int E, int nchunks,
    const float* __restrict__ x, const float* __restrict__ W1,
    unsigned short* __restrict__ hs, int n) {
    __shared__ alignas(16) char smem[SMEM_BYTES];
    int tid = threadIdx.x;
    if ((int)blockIdx.x < nchunks) {
        // ---------------- PART (21.5 KB) ----------------
        int* hist = (int*)smem;            // NBMAX (4 KB)
        int* gsh  = hist + NBMAX;          // NBMAX (4 KB)
        int* lex  = gsh + NBMAX;           // 256 (1 KB)
        int* stot = lex + 256;             // 4
        int* limg = stot + 4;              // CHUNK_P ints (8 KB)
        unsigned short* bid = (unsigned short*)(limg + CHUNK_P);  // 4 KB
        int e0  = blockIdx.x * CHUNK_P;
        int ds[CHUNK_P / 256], ss[CHUNK_P / 256];
#pragma unroll
        for (int j = 0; j < CHUNK_P / 256; j++) {
            int e = e0 + j * 256 + tid;
            if (e < E) { ds[j] = dst[e]; ss[j] = src[e]; } else ds[j] = -1;
        }
        hist[tid] = 0; hist[tid + 256] = 0;
        hist[tid + 512] = 0; hist[tid + 768] = 0;
        __syncthreads();
#pragma unroll
        for (int j = 0; j < CHUNK_P / 256; j++)
            if (ds[j] >= 0) atomicAdd(&hist[ds[j] >> BSH], 1);
        __syncthreads();
        int b0 = 4 * tid;
        int c0 = hist[b0], c1 = hist[b0 + 1], c2 = hist[b0 + 2], c3 = hist[b0 + 3];
        int s  = c0 + c1 + c2 + c3;
        lex[tid] = s;
        __syncthreads();
        for (int off = 1; off < 256; off <<= 1) {
            int v = lex[tid];
            int a = (tid >= off) ? lex[tid - off] : 0;
            __syncthreads();
            lex[tid] = v + a;
            __syncthreads();
        }
        int incl = lex[tid];
        if (tid == 255) stot[0] = incl;
        int ex0 = incl - s;
        int ex1 = ex0 + c0, ex2 = ex1 + c1, ex3 = ex2 + c2;
        int g0 = c0 ? atomicAdd(&gcur[b0], c0) : 0;
        int g1 = c1 ? atomicAdd(&gcur[b0 + 1], c1) : 0;
        int g2 = c2 ? atomicAdd(&gcur[b0 + 2], c2) : 0;
        int g3 = c3 ? atomicAdd(&gcur[b0 + 3], c3) : 0;
        hist[b0] = ex0; hist[b0 + 1] = ex1; hist[b0 + 2] = ex2; hist[b0 + 3] = ex3;
        gsh[b0]     = b0 * BCAP + g0 - ex0;
        gsh[b0 + 1] = (b0 + 1) * BCAP + g1 - ex1;
        gsh[b0 + 2] = (b0 + 2) * BCAP + g2 - ex2;
        gsh[b0 + 3] = (b0 + 3) * BCAP + g3 - ex3;
        __syncthreads();
#pragma unroll
        for (int j = 0; j < CHUNK_P / 256; j++) {
            if (ds[j] >= 0) {
                int b = ds[j] >> BSH;
                int p = atomicAdd(&hist[b], 1);
                limg[p] = (ss[j] << BSH) | (ds[j] & (((1 << BSH)) - 1));
                bid[p]  = (unsigned short)b;
            }
        }
        __syncthreads();
        int tot = stot[0];
        for (int k = tid; k < tot; k += 256)
            pairs[k + gsh[bid[k]]] = limg[k];
    } else {
        // ---------------- MM1: hs1 = bf16(x @ W1), UNSCALED (24.6 KB) -------
        unsigned short* Ws = (unsigned short*)smem;      // 16 KB, W1 as bf16
        float (*As)[MT] = (float(*)[MT])(smem + FIN * F1 * 2);  // 8 KB
        int n0 = ((int)blockIdx.x - nchunks) * MT;
#pragma unroll
        for (int j = 0; j < 8; j++) {
            int f = j * 256 + tid;                       // float4 index (2048)
            float4 w4 = ((const float4*)W1)[f];
            ushort4 o = { f2bf(w4.x), f2bf(w4.y), f2bf(w4.z), f2bf(w4.w) };
            ((ushort4*)Ws)[f] = o;
        }
        int m0 = (tid & 15) * 8;
        int c0 = (tid >> 4) * 4;
        int m_l = tid & 127;
        int kh  = (tid >> 7) * 8;
        bool mvalid = (n0 + m_l) < n;
        const float* xrow = x + (size_t)(n0 + m_l) * FIN + kh;
        float acc[8][4] = {};
        for (int kc = 0; kc < FIN; kc += KC) {
            __syncthreads();
            float4 v0 = mvalid ? *(const float4*)(xrow + kc)     : float4{0.f,0.f,0.f,0.f};
            float4 v1 = mvalid ? *(const float4*)(xrow + kc + 4) : float4{0.f,0.f,0.f,0.f};
            As[kh + 0][m_l] = v0.x; As[kh + 1][m_l] = v0.y;
            As[kh + 2][m_l] = v0.z; As[kh + 3][m_l] = v0.w;
            As[kh + 4][m_l] = v1.x; As[kh + 5][m_l] = v1.y;
            As[kh + 6][m_l] = v1.z; As[kh + 7][m_l] = v1.w;
            __syncthreads();
#pragma unroll
            for (int k = 0; k < KC; k++) {
                float4 a0 = *(const float4*)&As[k][m0];
                float4 a1 = *(const float4*)&As[k][m0 + 4];
                ushort4 wq = *(const ushort4*)&Ws[(kc + k) * F1 + c0];
                float wx = bf2f(wq.x), wy = bf2f(wq.y);
                float wz = bf2f(wq.z), ww = bf2f(wq.w);
                float a[8] = {a0.x, a0.y, a0.z, a0.w, a1.x, a1.y, a1.z, a1.w};
#pragma unroll
                for (int i = 0; i < 8; i++) {
                    acc[i][0] += a[i] * wx;
                    acc[i][1] += a[i] * wy;
                    acc[i][2] += a[i] * wz;
                    acc[i][3] += a[i] * ww;
                }
            }
        }
#pragma unroll
        for (int i = 0; i < 8; i++) {
            int node = n0 + m0 + i;
            if (node < n) {
                ushort4 o = { f2bf(acc[i][0]), f2bf(acc[i][1]),
                              f2bf(acc[i][2]), f2bf(acc[i][3]) };
                *(ushort4*)&hs[((size_t)node << 6) + c0] = o;
            }
        }
    }
}

// ---- pass 2: per-bucket CSR build + tail-scale hs1 by dinv -----------------
__global__ __launch_bounds__(256) void k_build(
    const int* __restrict__ gcur, const int* __restrict__ pairs,
    int* __restrict__ adjcur, int* __restrict__ adj,
    int2* __restrict__ rowinfo, float* __restrict__ dinv,
    unsigned short* __restrict__ hs1, int n) {
    __shared__ int lcnt[128];
    __shared__ int lex[128];
    __shared__ int lcur[128];
    __shared__ int ladj[BCAP];
    __shared__ float ldv[128];
    __shared__ int sbase;
    int tid = threadIdx.x;
    int b   = blockIdx.x;
    int cntb  = gcur[b]; if (cntb > BCAP) cntb = BCAP;
    int node0 = b << BSH;
    const int* pb = pairs + (size_t)b * BCAP;

    if (tid == 0) sbase = atomicAdd(adjcur, cntb);
    if (tid < 128) lcnt[tid] = 0;
    __syncthreads();
    for (int k = tid; k < cntb; k += 256) atomicAdd(&lcnt[pb[k] & 127], 1);
    __syncthreads();
    int own = (tid < 128) ? lcnt[tid] : 0;
    if (tid < 128) lex[tid] = own;
    __syncthreads();
    for (int off = 1; off < 128; off <<= 1) {
        int val = 0, add = 0;
        if (tid < 128) {
            val = lex[tid];
            add = (tid >= off) ? lex[tid - off] : 0;
        }
        __syncthreads();
        if (tid < 128) lex[tid] = val + add;
        __syncthreads();
    }
    int excl = (tid < 128) ? (lex[tid] - own) : 0;
    float dvn = rsqrtf((float)own + 1.0f);
    if (tid < 128) { lcur[tid] = excl; ldv[tid] = dvn; }
    __syncthreads();
    for (int k = tid; k < cntb; k += 256) {
        int pk  = pb[k];
        int pos = atomicAdd(&lcur[pk & 127], 1);
        ladj[pos] = pk >> BSH;
    }
    __syncthreads();
    int base = sbase;
    for (int k = tid; k < cntb; k += 256) adj[base + k] = ladj[k];
    int node = node0 + tid;
    if (tid < 128 && node < n) {
        rowinfo[node] = make_int2(base + excl, own);
        dinv[node]    = dvn;
    }
    // ---- tail: hs1[node] *= dinv[node] for this bucket's 128 nodes --------
    for (int u = tid; u < 1024; u += 256) {
        int nd = node0 + (u >> 3);
        if (nd >= n) break;
        float dv = ldv[u >> 3];
        ushort4* p = (ushort4*)&hs1[((size_t)nd << 6) + (u & 7) * 8];
        ushort4 a = p[0], c = p[1];
        a.x = f2bf(bf2f(a.x) * dv); a.y = f2bf(bf2f(a.y) * dv);
        a.z = f2bf(bf2f(a.z) * dv); a.w = f2bf(bf2f(a.w) * dv);
        c.x = f2bf(bf2f(c.x) * dv); c.y = f2bf(bf2f(c.y) * dv);
        c.z = f2bf(bf2f(c.z) * dv); c.w = f2bf(bf2f(c.w) * dv);
        p[0] = a; p[1] = c;
    }
}

// ---- layer 1 aggregate: h1 = bf16(relu(dinv*(gather+self) + b1)) -----------
__global__ __launch_bounds__(256) void k_agg1(
    const int2* __restrict__ rowinfo, const int* __restrict__ adj,
    const unsigned short* __restrict__ hs, const float* __restrict__ dinv,
    const float* __restrict__ b1, unsigned short* __restrict__ h1b, int n, int E) {
    int node = blockIdx.x * 4 + (threadIdx.x >> 6);
    if (node >= n) return;
    int lane = threadIdx.x & 63;
    int grp  = lane >> 4;
    int p4   = (lane & 15) * 4;
    int2 ri = rowinfo[node];
    int beg = ri.x, deg = ri.y;
    float4 acc = {0.f, 0.f, 0.f, 0.f};
    if (grp == 0) {                  // self-loop (pre-scaled)
        ushort4 u = *(const ushort4*)&hs[((size_t)node << 6) + p4];
        acc.x = bf2f(u.x); acc.y = bf2f(u.y); acc.z = bf2f(u.z); acc.w = bf2f(u.w);
    }
    for (int base = 0; base < deg; base += 64) {
        int m = deg - base; if (m > 64) m = 64;
        int idx = beg + base + lane;
        int myoff = adj[idx < E ? idx : 0] << 6;
        int e = 0;
        for (; e + 16 <= m; e += 16) {
            int o0 = __shfl(myoff, e + grp),      o1 = __shfl(myoff, e + 4 + grp);
            int o2 = __shfl(myoff, e + 8 + grp),  o3 = __shfl(myoff, e + 12 + grp);
            ushort4 u0 = *(const ushort4*)&hs[(size_t)o0 + p4];
            ushort4 u1 = *(const ushort4*)&hs[(size_t)o1 + p4];
            ushort4 u2 = *(const ushort4*)&hs[(size_t)o2 + p4];
            ushort4 u3 = *(const ushort4*)&hs[(size_t)o3 + p4];
            acc.x += (bf2f(u0.x) + bf2f(u1.x)) + (bf2f(u2.x) + bf2f(u3.x));
            acc.y += (bf2f(u0.y) + bf2f(u1.y)) + (bf2f(u2.y) + bf2f(u3.y));
            acc.z += (bf2f(u0.z) + bf2f(u1.z)) + (bf2f(u2.z) + bf2f(u3.z));
            acc.w += (bf2f(u0.w) + bf2f(u1.w)) + (bf2f(u2.w) + bf2f(u3.w));
        }
        for (; e < m; e += 4) {
            int sl = e + grp;
            int o = __shfl(myoff, sl);
            if (sl < m) {
                ushort4 u = *(const ushort4*)&hs[(size_t)o + p4];
                acc.x += bf2f(u.x); acc.y += bf2f(u.y);
                acc.z += bf2f(u.z); acc.w += bf2f(u.w);
            }
        }
    }
    acc.x += __shfl_xor(acc.x, 16); acc.y += __shfl_xor(acc.y, 16);
    acc.z += __shfl_xor(acc.z, 16); acc.w += __shfl_xor(acc.w, 16);
    acc.x += __shfl_xor(acc.x, 32); acc.y += __shfl_xor(acc.y, 32);
    acc.z += __shfl_xor(acc.z, 32); acc.w += __shfl_xor(acc.w, 32);
    if (grp == 0) {
        float dvn = dinv[node];
        float4 bg = *(const float4*)&b1[p4];
        float vx = acc.x * dvn + bg.x; vx = vx > 0.f ? vx : 0.f;
        float vy = acc.y * dvn + bg.y; vy = vy > 0.f ? vy : 0.f;
        float vz = acc.z * dvn + bg.z; vz = vz > 0.f ? vz : 0.f;
        float vw = acc.w * dvn + bg.w; vw = vw > 0.f ? vw : 0.f;
        ushort4 o = { f2bf(vx), f2bf(vy), f2bf(vz), f2bf(vw) };
        *(ushort4*)&h1b[((size_t)node << 6) + p4] = o;
    }
}

// ---- layer 2 GEMM (tiled): hs2 = bf16( (h1 @ W2) * dinv ), stride 64 -------
__global__ __launch_bounds__(256) void k_mm2(
    const unsigned short* __restrict__ h1b, const float* __restrict__ W2,
    const float* __restrict__ dinv, unsigned short* __restrict__ hs2, int n) {
    __shared__ float Ws[F1 * FP];    // 16 KB padded (cols 41..63 = 0)
    __shared__ float As[KC][MT];
    int t  = threadIdx.x;
    int n0 = blockIdx.x * MT;
    for (int idx = t; idx < F1 * FP; idx += 256) {
        int k = idx >> 6, c = idx & 63;
        Ws[idx] = (c < F2) ? W2[k * F2 + c] : 0.f;
    }
    int m0 = (t & 15) * 8;
    int c0 = (t >> 4) * 4;
    int m_l = t & 127;
    int kh  = (t >> 7) * 8;
    bool mvalid = (n0 + m_l) < n;
    const unsigned short* hrow = h1b + ((size_t)(n0 + m_l) << 6) + kh;
    float acc[8][4] = {};
    for (int kc = 0; kc < F1; kc += KC) {
        __syncthreads();
        ushort4 u0 = mvalid ? *(const ushort4*)(hrow + kc)     : ushort4{0,0,0,0};
        ushort4 u1 = mvalid ? *(const ushort4*)(hrow + kc + 4) : ushort4{0,0,0,0};
        As[kh + 0][m_l] = bf2f(u0.x); As[kh + 1][m_l] = bf2f(u0.y);
        As[kh + 2][m_l] = bf2f(u0.z); As[kh + 3][m_l] = bf2f(u0.w);
        As[kh + 4][m_l] = bf2f(u1.x); As[kh + 5][m_l] = bf2f(u1.y);
        As[kh + 6][m_l] = bf2f(u1.z); As[kh + 7][m_l] = bf2f(u1.w);
        __syncthreads();
#pragma unroll
        for (int k = 0; k < KC; k++) {
            float4 a0 = *(const float4*)&As[k][m0];
            float4 a1 = *(const float4*)&As[k][m0 + 4];
            float4 w  = *(const float4*)&Ws[(kc + k) * FP + c0];
            float a[8] = {a0.x, a0.y, a0.z, a0.w, a1.x, a1.y, a1.z, a1.w};
#pragma unroll
            for (int i = 0; i < 8; i++) {
                acc[i][0] += a[i] * w.x;
                acc[i][1] += a[i] * w.y;
                acc[i][2] += a[i] * w.z;
                acc[i][3] += a[i] * w.w;
            }
        }
    }
#pragma unroll
    for (int i = 0; i < 8; i++) {
        int node = n0 + m0 + i;
        if (node < n) {
            float dv = dinv[node];
            ushort4 o = { f2bf(acc[i][0] * dv), f2bf(acc[i][1] * dv),
                          f2bf(acc[i][2] * dv), f2bf(acc[i][3] * dv) };
            *(ushort4*)&hs2[((size_t)node << 6) + c0] = o;
        }
    }
}

// ---- layer 2 aggregate: out = dinv*(gather+self) + b2 ----------------------
__global__ __launch_bounds__(256) void k_agg2(
    const int2* __restrict__ rowinfo, const int* __restrict__ adj,
    const unsigned short* __restrict__ hs2, const float* __restrict__ dinv,
    const float* __restrict__ b2, float* __restrict__ out, int n, int E) {
    int node = blockIdx.x * 4 + (threadIdx.x >> 6);
    if (node >= n) return;
    int lane = threadIdx.x & 63;
    int grp  = lane >> 4;
    int p4   = (lane & 15) * 4;
    int2 ri = rowinfo[node];
    int beg = ri.x, deg = ri.y;
    float4 acc = {0.f, 0.f, 0.f, 0.f};
    if (grp == 0) {
        ushort4 u = *(const ushort4*)&hs2[((size_t)node << 6) + p4];
        acc.x = bf2f(u.x); acc.y = bf2f(u.y); acc.z = bf2f(u.z); acc.w = bf2f(u.w);
    }
    for (int base = 0; base < deg; base += 64) {
        int m = deg - base; if (m > 64) m = 64;
        int idx = beg + base + lane;
        int myoff = adj[idx < E ? idx : 0] << 6;
        int e = 0;
        for (; e + 16 <= m; e += 16) {
            int o0 = __shfl(myoff, e + grp),      o1 = __shfl(myoff, e + 4 + grp);
            int o2 = __shfl(myoff, e + 8 + grp),  o3 = __shfl(myoff, e + 12 + grp);
            ushort4 u0 = *(const ushort4*)&hs2[(size_t)o0 + p4];
            ushort4 u1 = *(const ushort4*)&hs2[(size_t)o1 + p4];
            ushort4 u2 = *(const ushort4*)&hs2[(size_t)o2 + p4];
            ushort4 u3 = *(const ushort4*)&hs2[(size_t)o3 + p4];
            acc.x += (bf2f(u0.x) + bf2f(u1.x)) + (bf2f(u2.x) + bf2f(u3.x));
            acc.y += (bf2f(u0.y) + bf2f(u1.y)) + (bf2f(u2.y) + bf2f(u3.y));
            acc.z += (bf2f(u0.z) + bf2f(u1.z)) + (bf2f(u2.z) + bf2f(u3.z));
            acc.w += (bf2f(u0.w) + bf2f(u1.w)) + (bf2f(u2.w) + bf2f(u3.w));
        }
        for (; e < m; e += 4) {
            int sl = e + grp;
            int o = __shfl(myoff, sl);
            if (sl < m) {
                ushort4 u = *(const ushort4*)&hs2[(size_t)o + p4];
                acc.x += bf2f(u.x); acc.y += bf2f(u.y);
                acc.z += bf2f(u.z); acc.w += bf2f(u.w);
            }
        }
    }
    acc.x += __shfl_xor(acc.x, 16); acc.y += __shfl_xor(acc.y, 16);
    acc.z += __shfl_xor(acc.z, 16); acc.w += __shfl_xor(acc.w, 16);
    acc.x += __shfl_xor(acc.x, 32); acc.y += __shfl_xor(acc.y, 32);
    acc.z += __shfl_xor(acc.z, 32); acc.w += __shfl_xor(acc.w, 32);
    if (grp == 0) {
        float dv = dinv[node];
        float vv[4] = {acc.x, acc.y, acc.z, acc.w};
#pragma unroll
        for (int j = 0; j < 4; j++) {
            int f = p4 + j;
            if (f < F2) out[(size_t)node * F2 + f] = vv[j] * dv + b2[f];
        }
    }
}

extern "C" void kernel_launch(void* const* d_in, const int* in_sizes, int n_in,
                              void* d_out, int out_size, void* d_ws, size_t ws_size,
                              hipStream_t stream) {
    const float* x  = (const float*)d_in[0];
    const int*   ei = (const int*)d_in[1];
    const float* W1 = (const float*)d_in[2];
    const float* b1 = (const float*)d_in[3];
    const float* W2 = (const float*)d_in[4];
    const float* b2 = (const float*)d_in[5];
    float* out = (float*)d_out;

    const int n = in_sizes[0] / FIN;   // 100000
    const int E = in_sizes[1] / 2;     // 1600000
    const int* src = ei;
    const int* dst = ei + E;
    const int nbuck   = (n + (1 << BSH) - 1) >> BSH;   // 782 (<= NBMAX)
    const int nchunks = (E + CHUNK_P - 1) / CHUNK_P;   // 782
    const int nmm     = (n + MT - 1) / MT;             // 782
    const int nagg    = (n + 3) / 4;                   // 25000

    char* ws = (char*)d_ws;
    size_t off = 0;
    auto alloc = [&](size_t bytes) {
        void* p = ws + off;
        off = (off + bytes + 511) & ~(size_t)511;
        return p;
    };
    int*   gcur    = (int*)alloc((size_t)(NBMAX + 1) * 4);  // [NBMAX] = adj cursor
    int*   pairs   = (int*)alloc((size_t)nbuck * BCAP * 4); // ~9.6 MB
    int*   adj     = (int*)alloc((size_t)E * 4);
    int2*  rowinfo = (int2*)alloc((size_t)n * 8);
    float* dinv    = (float*)alloc((size_t)n * 4);
    unsigned short* hs1 = (unsigned short*)alloc((size_t)n * FP * 2);
    unsigned short* hs2 = (unsigned short*)alloc((size_t)n * FP * 2);
    unsigned short* h1b = (unsigned short*)alloc((size_t)n * FP * 2);

    hipMemsetAsync(gcur, 0, (size_t)(NBMAX + 1) * 4, stream);
    k_partmm1<<<nchunks + nmm, 256, 0, stream>>>(src, dst, gcur, pairs, E, nchunks,
                                                 x, W1, hs1, n);
    k_build<<<nbuck, 256, 0, stream>>>(gcur, pairs, gcur + NBMAX, adj, rowinfo,
                                       dinv, hs1, n);
    k_agg1<<<nagg, 256, 0, stream>>>(rowinfo, adj, hs1, dinv, b1, h1b, n, E);
    k_mm2<<<nmm, 256, 0, stream>>>(h1b, W2, dinv, hs2, n);
    k_agg2<<<nagg, 256, 0, stream>>>(rowinfo, adj, hs2, dinv, b2, out, n, E);
}

// Round 2
// 293.700 us; speedup vs baseline: 1.1483x; 1.1483x over previous
//
#include <hip/hip_runtime.h>

// GCN 2-layer forward. CSR-gather, bf16 payloads (stride-64, 128 B rows),
// 4-edges-per-gather aggregation. hs1 = x@W1 (unscaled; mm1 fused with part,
// build pre-scales hs1 by dinv). Pipeline (5 dispatches): partmm1 ->
// build(+scale) -> agg1 -> mm2 -> agg2.
//
// R2: partition made atomic-free and fully coalesced. R1 showed the pairs
// scatter into global bucket windows (gcur atomics) caused partial-line
// write-allocate RMW (WRITE_SIZE 23->40 MB at finer granularity). Now each
// chunk writes its LDS-sorted run CONTIGUOUSLY (pairs[chunk*4096+k]) plus a
// u16 per-chunk bucket-offset row; build gathers per-bucket segments from the
// L3-resident pairs (reads, not RMW writes) and places into a static
// per-bucket adj window (b*BCAP). gcur + memset dispatch eliminated.

#define FIN 128
#define F1  64
#define F2  41
#define FP  64     // payload row stride (bf16 elems): 128 B, 2 lines, aligned

#define BSH    8                 // bucket = dst >> 8 (256 nodes/bucket)
#define BCAP   6144              // per-bucket adj window (mean 4096, >30 sigma)
#define CHUNK_P 4096             // edges per part block (16/thread)

#define MT 128                   // GEMM M-tile
#define KC 16                    // GEMM K-chunk

#define SMEM_BYTES 24576         // union: part 19.5 KB / mm1 24.6 KB -> 6 blk/CU

__device__ __forceinline__ unsigned short f2bf(float f) {
    unsigned u = __builtin_bit_cast(unsigned, f);
    u += 0x7FFFu + ((u >> 16) & 1u);           // RNE
    return (unsigned short)(u >> 16);
}
__device__ __forceinline__ float bf2f(unsigned short h) {
    unsigned u = ((unsigned)h) << 16;
    return __builtin_bit_cast(float, u);
}

// ---- fused: blocks [0,nchunks) = edge partition; rest = layer-1 GEMM -------
__global__ __launch_bounds__(256) void k_partmm1(
    const int* __restrict__ src, const int* __restrict__ dst,
    unsigned short* __restrict__ offs, int* __restrict__ pairs,
    int E, int nchunks, int NB,
    const float* __restrict__ x, const float* __restrict__ W1,
    unsigned short* __restrict__ hs, int n) {
    __shared__ alignas(16) char smem[SMEM_BYTES];
    int tid = threadIdx.x;
    if ((int)blockIdx.x < nchunks) {
        // ---------------- PART (19.5 KB): LDS bucket-sort, coalesced out ----
        int* hist = (int*)smem;            // 512 ints (2 KB)
        int* lex  = hist + 512;            // 256 (1 KB)
        int* limg = lex + 256;             // CHUNK_P ints (16 KB)
        int e0  = blockIdx.x * CHUNK_P;
        int ds[CHUNK_P / 256], ss[CHUNK_P / 256];
#pragma unroll
        for (int j = 0; j < CHUNK_P / 256; j++) {
            int e = e0 + j * 256 + tid;
            if (e < E) { ds[j] = dst[e]; ss[j] = src[e]; } else ds[j] = -1;
        }
        hist[tid] = 0; hist[tid + 256] = 0;
        __syncthreads();
#pragma unroll
        for (int j = 0; j < CHUNK_P / 256; j++)
            if (ds[j] >= 0) atomicAdd(&hist[ds[j] >> BSH], 1);
        __syncthreads();
        int b0 = 2 * tid, b1 = 2 * tid + 1;
        int c0 = hist[b0], c1 = hist[b1];
        int s  = c0 + c1;
        lex[tid] = s;
        __syncthreads();
        for (int off = 1; off < 256; off <<= 1) {
            int v = lex[tid];
            int a = (tid >= off) ? lex[tid - off] : 0;
            __syncthreads();
            lex[tid] = v + a;
            __syncthreads();
        }
        int incl = lex[tid];
        int ex0 = incl - s;
        int ex1 = ex0 + c0;
        // per-chunk bucket offset row (u16): starts[b], plus total at [NB]
        unsigned short* orow = offs + (size_t)blockIdx.x * (NB + 1);
        if (b0 < NB) orow[b0] = (unsigned short)ex0;
        if (b1 < NB) orow[b1] = (unsigned short)ex1;
        if (tid == 255) orow[NB] = (unsigned short)incl;
        hist[b0] = ex0; hist[b1] = ex1;
        __syncthreads();
#pragma unroll
        for (int j = 0; j < CHUNK_P / 256; j++) {
            if (ds[j] >= 0) {
                int b = ds[j] >> BSH;
                int p = atomicAdd(&hist[b], 1);
                limg[p] = (ss[j] << BSH) | (ds[j] & 255);
            }
        }
        __syncthreads();
        int tot = lex[255];
        int* pout = pairs + (size_t)blockIdx.x * CHUNK_P;
        for (int k = tid; k < tot; k += 256)   // fully coalesced
            pout[k] = limg[k];
    } else {
        // ---------------- MM1: hs1 = bf16(x @ W1), UNSCALED (24.6 KB) -------
        unsigned short* Ws = (unsigned short*)smem;      // 16 KB, W1 as bf16
        float (*As)[MT] = (float(*)[MT])(smem + FIN * F1 * 2);  // 8 KB
        int n0 = ((int)blockIdx.x - nchunks) * MT;
#pragma unroll
        for (int j = 0; j < 8; j++) {
            int f = j * 256 + tid;                       // float4 index (2048)
            float4 w4 = ((const float4*)W1)[f];
            ushort4 o = { f2bf(w4.x), f2bf(w4.y), f2bf(w4.z), f2bf(w4.w) };
            ((ushort4*)Ws)[f] = o;
        }
        int m0 = (tid & 15) * 8;
        int c0 = (tid >> 4) * 4;
        int m_l = tid & 127;
        int kh  = (tid >> 7) * 8;
        bool mvalid = (n0 + m_l) < n;
        const float* xrow = x + (size_t)(n0 + m_l) * FIN + kh;
        float acc[8][4] = {};
        for (int kc = 0; kc < FIN; kc += KC) {
            __syncthreads();
            float4 v0 = mvalid ? *(const float4*)(xrow + kc)     : float4{0.f,0.f,0.f,0.f};
            float4 v1 = mvalid ? *(const float4*)(xrow + kc + 4) : float4{0.f,0.f,0.f,0.f};
            As[kh + 0][m_l] = v0.x; As[kh + 1][m_l] = v0.y;
            As[kh + 2][m_l] = v0.z; As[kh + 3][m_l] = v0.w;
            As[kh + 4][m_l] = v1.x; As[kh + 5][m_l] = v1.y;
            As[kh + 6][m_l] = v1.z; As[kh + 7][m_l] = v1.w;
            __syncthreads();
#pragma unroll
            for (int k = 0; k < KC; k++) {
                float4 a0 = *(const float4*)&As[k][m0];
                float4 a1 = *(const float4*)&As[k][m0 + 4];
                ushort4 wq = *(const ushort4*)&Ws[(kc + k) * F1 + c0];
                float wx = bf2f(wq.x), wy = bf2f(wq.y);
                float wz = bf2f(wq.z), ww = bf2f(wq.w);
                float a[8] = {a0.x, a0.y, a0.z, a0.w, a1.x, a1.y, a1.z, a1.w};
#pragma unroll
                for (int i = 0; i < 8; i++) {
                    acc[i][0] += a[i] * wx;
                    acc[i][1] += a[i] * wy;
                    acc[i][2] += a[i] * wz;
                    acc[i][3] += a[i] * ww;
                }
            }
        }
#pragma unroll
        for (int i = 0; i < 8; i++) {
            int node = n0 + m0 + i;
            if (node < n) {
                ushort4 o = { f2bf(acc[i][0]), f2bf(acc[i][1]),
                              f2bf(acc[i][2]), f2bf(acc[i][3]) };
                *(ushort4*)&hs[((size_t)node << 6) + c0] = o;
            }
        }
    }
}

// ---- pass 2: per-bucket CSR build (segment gather) + tail-scale hs1 --------
__global__ __launch_bounds__(256) void k_build(
    const unsigned short* __restrict__ offs, const int* __restrict__ pairs,
    int nchunks, int NB, int* __restrict__ adj,
    int2* __restrict__ rowinfo, float* __restrict__ dinv,
    unsigned short* __restrict__ hs1, int n) {
    __shared__ int lcnt[256];
    __shared__ int lex[256];
    __shared__ int lcur[256];
    __shared__ float ldv[256];
    int tid = threadIdx.x;
    int b   = blockIdx.x;
    int NB1 = NB + 1;
    int node0 = b << BSH;
    int base  = b * BCAP;              // static adj window

    lcnt[tid] = 0;
    __syncthreads();
    // pass 1: per-node histogram from this bucket's segments (L3-resident)
    for (int c = tid; c < nchunks; c += 256) {
        int s0 = offs[(size_t)c * NB1 + b];
        int s1 = offs[(size_t)c * NB1 + b + 1];
        const int* pc = pairs + (size_t)c * CHUNK_P;
        for (int i = s0; i < s1; i++) atomicAdd(&lcnt[pc[i] & 255], 1);
    }
    __syncthreads();
    int own = lcnt[tid];
    lex[tid] = own;
    __syncthreads();
    for (int off = 1; off < 256; off <<= 1) {
        int val = lex[tid];
        int add = (tid >= off) ? lex[tid - off] : 0;
        __syncthreads();
        lex[tid] = val + add;
        __syncthreads();
    }
    int excl = lex[tid] - own;
    float dvn = rsqrtf((float)own + 1.0f);
    lcur[tid] = excl;
    ldv[tid]  = dvn;
    __syncthreads();
    // pass 2: place src ids directly into the L2-resident adj window
    for (int c = tid; c < nchunks; c += 256) {
        int s0 = offs[(size_t)c * NB1 + b];
        int s1 = offs[(size_t)c * NB1 + b + 1];
        const int* pc = pairs + (size_t)c * CHUNK_P;
        for (int i = s0; i < s1; i++) {
            int pk  = pc[i];
            int pos = atomicAdd(&lcur[pk & 255], 1);
            adj[base + pos] = pk >> BSH;
        }
    }
    int node = node0 + tid;
    if (node < n) {
        rowinfo[node] = make_int2(base + excl, own);
        dinv[node]    = dvn;
    }
    // ---- tail: hs1[node] *= dinv[node] for this bucket's 256 nodes --------
    for (int u = tid; u < 2048; u += 256) {
        int nd = node0 + (u >> 3);
        if (nd >= n) break;
        float dv = ldv[u >> 3];
        ushort4* p = (ushort4*)&hs1[((size_t)nd << 6) + (u & 7) * 8];
        ushort4 a = p[0], c = p[1];
        a.x = f2bf(bf2f(a.x) * dv); a.y = f2bf(bf2f(a.y) * dv);
        a.z = f2bf(bf2f(a.z) * dv); a.w = f2bf(bf2f(a.w) * dv);
        c.x = f2bf(bf2f(c.x) * dv); c.y = f2bf(bf2f(c.y) * dv);
        c.z = f2bf(bf2f(c.z) * dv); c.w = f2bf(bf2f(c.w) * dv);
        p[0] = a; p[1] = c;
    }
}

// ---- layer 1 aggregate: h1 = bf16(relu(dinv*(gather+self) + b1)) -----------
__global__ __launch_bounds__(256) void k_agg1(
    const int2* __restrict__ rowinfo, const int* __restrict__ adj,
    const unsigned short* __restrict__ hs, const float* __restrict__ dinv,
    const float* __restrict__ b1, unsigned short* __restrict__ h1b, int n, int AT) {
    int node = blockIdx.x * 4 + (threadIdx.x >> 6);
    if (node >= n) return;
    int lane = threadIdx.x & 63;
    int grp  = lane >> 4;
    int p4   = (lane & 15) * 4;
    int2 ri = rowinfo[node];
    int beg = ri.x, deg = ri.y;
    float4 acc = {0.f, 0.f, 0.f, 0.f};
    if (grp == 0) {                  // self-loop (pre-scaled)
        ushort4 u = *(const ushort4*)&hs[((size_t)node << 6) + p4];
        acc.x = bf2f(u.x); acc.y = bf2f(u.y); acc.z = bf2f(u.z); acc.w = bf2f(u.w);
    }
    for (int base = 0; base < deg; base += 64) {
        int m = deg - base; if (m > 64) m = 64;
        int idx = beg + base + lane;
        int myoff = adj[idx < AT ? idx : 0] << 6;
        int e = 0;
        for (; e + 16 <= m; e += 16) {
            int o0 = __shfl(myoff, e + grp),      o1 = __shfl(myoff, e + 4 + grp);
            int o2 = __shfl(myoff, e + 8 + grp),  o3 = __shfl(myoff, e + 12 + grp);
            ushort4 u0 = *(const ushort4*)&hs[(size_t)o0 + p4];
            ushort4 u1 = *(const ushort4*)&hs[(size_t)o1 + p4];
            ushort4 u2 = *(const ushort4*)&hs[(size_t)o2 + p4];
            ushort4 u3 = *(const ushort4*)&hs[(size_t)o3 + p4];
            acc.x += (bf2f(u0.x) + bf2f(u1.x)) + (bf2f(u2.x) + bf2f(u3.x));
            acc.y += (bf2f(u0.y) + bf2f(u1.y)) + (bf2f(u2.y) + bf2f(u3.y));
            acc.z += (bf2f(u0.z) + bf2f(u1.z)) + (bf2f(u2.z) + bf2f(u3.z));
            acc.w += (bf2f(u0.w) + bf2f(u1.w)) + (bf2f(u2.w) + bf2f(u3.w));
        }
        for (; e < m; e += 4) {
            int sl = e + grp;
            int o = __shfl(myoff, sl);
            if (sl < m) {
                ushort4 u = *(const ushort4*)&hs[(size_t)o + p4];
                acc.x += bf2f(u.x); acc.y += bf2f(u.y);
                acc.z += bf2f(u.z); acc.w += bf2f(u.w);
            }
        }
    }
    acc.x += __shfl_xor(acc.x, 16); acc.y += __shfl_xor(acc.y, 16);
    acc.z += __shfl_xor(acc.z, 16); acc.w += __shfl_xor(acc.w, 16);
    acc.x += __shfl_xor(acc.x, 32); acc.y += __shfl_xor(acc.y, 32);
    acc.z += __shfl_xor(acc.z, 32); acc.w += __shfl_xor(acc.w, 32);
    if (grp == 0) {
        float dvn = dinv[node];
        float4 bg = *(const float4*)&b1[p4];
        float vx = acc.x * dvn + bg.x; vx = vx > 0.f ? vx : 0.f;
        float vy = acc.y * dvn + bg.y; vy = vy > 0.f ? vy : 0.f;
        float vz = acc.z * dvn + bg.z; vz = vz > 0.f ? vz : 0.f;
        float vw = acc.w * dvn + bg.w; vw = vw > 0.f ? vw : 0.f;
        ushort4 o = { f2bf(vx), f2bf(vy), f2bf(vz), f2bf(vw) };
        *(ushort4*)&h1b[((size_t)node << 6) + p4] = o;
    }
}

// ---- layer 2 GEMM (tiled): hs2 = bf16( (h1 @ W2) * dinv ), stride 64 -------
__global__ __launch_bounds__(256) void k_mm2(
    const unsigned short* __restrict__ h1b, const float* __restrict__ W2,
    const float* __restrict__ dinv, unsigned short* __restrict__ hs2, int n) {
    __shared__ float Ws[F1 * FP];    // 16 KB padded (cols 41..63 = 0)
    __shared__ float As[KC][MT];
    int t  = threadIdx.x;
    int n0 = blockIdx.x * MT;
    for (int idx = t; idx < F1 * FP; idx += 256) {
        int k = idx >> 6, c = idx & 63;
        Ws[idx] = (c < F2) ? W2[k * F2 + c] : 0.f;
    }
    int m0 = (t & 15) * 8;
    int c0 = (t >> 4) * 4;
    int m_l = t & 127;
    int kh  = (t >> 7) * 8;
    bool mvalid = (n0 + m_l) < n;
    const unsigned short* hrow = h1b + ((size_t)(n0 + m_l) << 6) + kh;
    float acc[8][4] = {};
    for (int kc = 0; kc < F1; kc += KC) {
        __syncthreads();
        ushort4 u0 = mvalid ? *(const ushort4*)(hrow + kc)     : ushort4{0,0,0,0};
        ushort4 u1 = mvalid ? *(const ushort4*)(hrow + kc + 4) : ushort4{0,0,0,0};
        As[kh + 0][m_l] = bf2f(u0.x); As[kh + 1][m_l] = bf2f(u0.y);
        As[kh + 2][m_l] = bf2f(u0.z); As[kh + 3][m_l] = bf2f(u0.w);
        As[kh + 4][m_l] = bf2f(u1.x); As[kh + 5][m_l] = bf2f(u1.y);
        As[kh + 6][m_l] = bf2f(u1.z); As[kh + 7][m_l] = bf2f(u1.w);
        __syncthreads();
#pragma unroll
        for (int k = 0; k < KC; k++) {
            float4 a0 = *(const float4*)&As[k][m0];
            float4 a1 = *(const float4*)&As[k][m0 + 4];
            float4 w  = *(const float4*)&Ws[(kc + k) * FP + c0];
            float a[8] = {a0.x, a0.y, a0.z, a0.w, a1.x, a1.y, a1.z, a1.w};
#pragma unroll
            for (int i = 0; i < 8; i++) {
                acc[i][0] += a[i] * w.x;
                acc[i][1] += a[i] * w.y;
                acc[i][2] += a[i] * w.z;
                acc[i][3] += a[i] * w.w;
            }
        }
    }
#pragma unroll
    for (int i = 0; i < 8; i++) {
        int node = n0 + m0 + i;
        if (node < n) {
            float dv = dinv[node];
            ushort4 o = { f2bf(acc[i][0] * dv), f2bf(acc[i][1] * dv),
                          f2bf(acc[i][2] * dv), f2bf(acc[i][3] * dv) };
            *(ushort4*)&hs2[((size_t)node << 6) + c0] = o;
        }
    }
}

// ---- layer 2 aggregate: out = dinv*(gather+self) + b2 ----------------------
__global__ __launch_bounds__(256) void k_agg2(
    const int2* __restrict__ rowinfo, const int* __restrict__ adj,
    const unsigned short* __restrict__ hs2, const float* __restrict__ dinv,
    const float* __restrict__ b2, float* __restrict__ out, int n, int AT) {
    int node = blockIdx.x * 4 + (threadIdx.x >> 6);
    if (node >= n) return;
    int lane = threadIdx.x & 63;
    int grp  = lane >> 4;
    int p4   = (lane & 15) * 4;
    int2 ri = rowinfo[node];
    int beg = ri.x, deg = ri.y;
    float4 acc = {0.f, 0.f, 0.f, 0.f};
    if (grp == 0) {
        ushort4 u = *(const ushort4*)&hs2[((size_t)node << 6) + p4];
        acc.x = bf2f(u.x); acc.y = bf2f(u.y); acc.z = bf2f(u.z); acc.w = bf2f(u.w);
    }
    for (int base = 0; base < deg; base += 64) {
        int m = deg - base; if (m > 64) m = 64;
        int idx = beg + base + lane;
        int myoff = adj[idx < AT ? idx : 0] << 6;
        int e = 0;
        for (; e + 16 <= m; e += 16) {
            int o0 = __shfl(myoff, e + grp),      o1 = __shfl(myoff, e + 4 + grp);
            int o2 = __shfl(myoff, e + 8 + grp),  o3 = __shfl(myoff, e + 12 + grp);
            ushort4 u0 = *(const ushort4*)&hs2[(size_t)o0 + p4];
            ushort4 u1 = *(const ushort4*)&hs2[(size_t)o1 + p4];
            ushort4 u2 = *(const ushort4*)&hs2[(size_t)o2 + p4];
            ushort4 u3 = *(const ushort4*)&hs2[(size_t)o3 + p4];
            acc.x += (bf2f(u0.x) + bf2f(u1.x)) + (bf2f(u2.x) + bf2f(u3.x));
            acc.y += (bf2f(u0.y) + bf2f(u1.y)) + (bf2f(u2.y) + bf2f(u3.y));
            acc.z += (bf2f(u0.z) + bf2f(u1.z)) + (bf2f(u2.z) + bf2f(u3.z));
            acc.w += (bf2f(u0.w) + bf2f(u1.w)) + (bf2f(u2.w) + bf2f(u3.w));
        }
        for (; e < m; e += 4) {
            int sl = e + grp;
            int o = __shfl(myoff, sl);
            if (sl < m) {
                ushort4 u = *(const ushort4*)&hs2[(size_t)o + p4];
                acc.x += bf2f(u.x); acc.y += bf2f(u.y);
                acc.z += bf2f(u.z); acc.w += bf2f(u.w);
            }
        }
    }
    acc.x += __shfl_xor(acc.x, 16); acc.y += __shfl_xor(acc.y, 16);
    acc.z += __shfl_xor(acc.z, 16); acc.w += __shfl_xor(acc.w, 16);
    acc.x += __shfl_xor(acc.x, 32); acc.y += __shfl_xor(acc.y, 32);
    acc.z += __shfl_xor(acc.z, 32); acc.w += __shfl_xor(acc.w, 32);
    if (grp == 0) {
        float dv = dinv[node];
        float vv[4] = {acc.x, acc.y, acc.z, acc.w};
#pragma unroll
        for (int j = 0; j < 4; j++) {
            int f = p4 + j;
            if (f < F2) out[(size_t)node * F2 + f] = vv[j] * dv + b2[f];
        }
    }
}

extern "C" void kernel_launch(void* const* d_in, const int* in_sizes, int n_in,
                              void* d_out, int out_size, void* d_ws, size_t ws_size,
                              hipStream_t stream) {
    const float* x  = (const float*)d_in[0];
    const int*   ei = (const int*)d_in[1];
    const float* W1 = (const float*)d_in[2];
    const float* b1 = (const float*)d_in[3];
    const float* W2 = (const float*)d_in[4];
    const float* b2 = (const float*)d_in[5];
    float* out = (float*)d_out;

    const int n = in_sizes[0] / FIN;   // 100000
    const int E = in_sizes[1] / 2;     // 1600000
    const int* src = ei;
    const int* dst = ei + E;
    const int nbuck   = (n + 255) >> BSH;              // 391
    const int nchunks = (E + CHUNK_P - 1) / CHUNK_P;   // 391
    const int nmm     = (n + MT - 1) / MT;             // 782
    const int nagg    = (n + 3) / 4;                   // 25000
    const int adjtot  = nbuck * BCAP;

    char* ws = (char*)d_ws;
    size_t off = 0;
    auto alloc = [&](size_t bytes) {
        void* p = ws + off;
        off = (off + bytes + 511) & ~(size_t)511;
        return p;
    };
    unsigned short* offs = (unsigned short*)alloc((size_t)nchunks * (nbuck + 1) * 2);
    int*   pairs   = (int*)alloc((size_t)nchunks * CHUNK_P * 4); // 6.4 MB
    int*   adj     = (int*)alloc((size_t)adjtot * 4 + 256);      // 9.6 MB
    int2*  rowinfo = (int2*)alloc((size_t)n * 8);
    float* dinv    = (float*)alloc((size_t)n * 4);
    unsigned short* hs1 = (unsigned short*)alloc((size_t)n * FP * 2);
    unsigned short* hs2 = (unsigned short*)alloc((size_t)n * FP * 2);
    unsigned short* h1b = (unsigned short*)alloc((size_t)n * FP * 2);

    k_partmm1<<<nchunks + nmm, 256, 0, stream>>>(src, dst, offs, pairs, E, nchunks,
                                                 nbuck, x, W1, hs1, n);
    k_build<<<nbuck, 256, 0, stream>>>(offs, pairs, nchunks, nbuck, adj, rowinfo,
                                       dinv, hs1, n);
    k_agg1<<<nagg, 256, 0, stream>>>(rowinfo, adj, hs1, dinv, b1, h1b, n, adjtot);
    k_mm2<<<nmm, 256, 0, stream>>>(h1b, W2, dinv, hs2, n);
    k_agg2<<<nagg, 256, 0, stream>>>(rowinfo, adj, hs2, dinv, b2, out, n, adjtot);
}